// Round 8
// baseline (157.868 us; speedup 1.0000x reference)
//
#include <hip/hip_runtime.h>
#include <math.h>

#define B_ 8
#define T_ 2048
#define D_ 1024
#define HS_ 64

typedef _Float16 f16x8 __attribute__((ext_vector_type(8)));
typedef _Float16 f16x4 __attribute__((ext_vector_type(4)));
typedef float f32x4 __attribute__((ext_vector_type(4)));

typedef __attribute__((address_space(3))) void       lds_void;
typedef const __attribute__((address_space(1))) void gbl_void;
__device__ static inline void async_ld16(gbl_void* g, lds_void* l) {
    // 16 B per lane, HW dest = lds_base + lane*16 (wave-uniform base)
    __builtin_amdgcn_global_load_lds(g, l, 16, 0, 0);
}

// ---------------------------------------------------------------------------
// ws layout (f16 elements unless noted):
//   qf    : [B*T][64]        @ 0          (1,048,576)
//   kf    : [B*T][64]        @ 1,048,576
//   vT    : [B][64][T]       @ 2,097,152
//   Wfrag : fragment-packed  @ 3,145,728  (196,608)
//   Op    : [1152][64][64]   @ 3,342,336  (4,718,592) unnormalized O partials
//   ml    : [1152][128] f32  @ f16-idx 8,060,928  (m[64] then l[64] per slot)
// ---------------------------------------------------------------------------

// Stage 0: Wq|Wk|Wv (fp32 [1024][64]) -> Wfrag (f16, MFMA-fragment order)
__global__ __launch_bounds__(256) void wt_kernel(
    const float* __restrict__ Wq, const float* __restrict__ Wk,
    const float* __restrict__ Wv, _Float16* __restrict__ Wfrag)
{
    __shared__ _Float16 Tt[64][72];   // Tt[h][k_local]
    const int my = blockIdx.y;        // matrix 0,1,2
    const float* W = (my == 0) ? Wq : (my == 1) ? Wk : Wv;
    const int t  = threadIdx.x;
    const int kb = blockIdx.x;        // 64-k block
    const int k0 = kb * 64;
    {
        const int r = t >> 2, c0 = (t & 3) * 16;   // r = k row, c0 = h base
#pragma unroll
        for (int i = 0; i < 4; ++i) {
            float4 w = *(const float4*)&W[(size_t)(k0 + r) * HS_ + c0 + i * 4];
            Tt[c0 + i * 4 + 0][r] = (_Float16)w.x;
            Tt[c0 + i * 4 + 1][r] = (_Float16)w.y;
            Tt[c0 + i * 4 + 2][r] = (_Float16)w.z;
            Tt[c0 + i * 4 + 3][r] = (_Float16)w.w;
        }
    }
    __syncthreads();
    {
        const int lane = t & 63, j = t >> 6;       // j = n-tile within matrix
        const int lid = lane & 15, quad = lane >> 4;
        const int c = kb >> 1, shalf = kb & 1;
        const int nt = my * 4 + j;
#pragma unroll
        for (int s2 = 0; s2 < 2; ++s2) {
            const int u = (c * 12 + nt) * 4 + shalf * 2 + s2;
            *(int4*)&Wfrag[(size_t)u * 512 + lane * 8] =
                *(int4*)&Tt[j * 16 + lid][s2 * 32 + quad * 8];
        }
    }
}

// ---------------------------------------------------------------------------
// Stage 1: QKV projection (unchanged from Round 7).
// ---------------------------------------------------------------------------
__global__ __launch_bounds__(256, 2) void qkv_kernel(
    const float* __restrict__ x, const _Float16* __restrict__ Wfrag,
    _Float16* __restrict__ qf, _Float16* __restrict__ kf,
    _Float16* __restrict__ vT)
{
    __shared__ __align__(16) char smem[65792];        // Xs 16640 | Ws 49152
    _Float16* Ws = (_Float16*)(smem + 16640);
    _Float16 (*CsH)[200] = (_Float16(*)[200])smem;     // epilogue overlay

    const int t    = threadIdx.x;
    const int m0   = blockIdx.x * 32;
    const int lane = t & 63, wave = t >> 6;
    const int lid  = lane & 15, quad = lane >> 4;
    const int mt   = wave & 1;          // row group (16 rows)
    const int nh   = wave >> 1;         // n-half (6 n-tiles)

    f32x4 acc[6];
#pragma unroll
    for (int i = 0; i < 6; ++i) acc[i] = f32x4{0.f, 0.f, 0.f, 0.f};

    for (int c = 0; c < 8; ++c) {
        const int kc = c * 128;
        __syncthreads();   // previous chunk's LDS reads complete
#pragma unroll
        for (int i = 0; i < 4; ++i) {
            const int xu = wave * 4 + i;
            const float* g = x + (size_t)(m0 + xu * 2 + (lane >> 5)) * D_
                             + kc + (lane & 31) * 4;
            async_ld16((gbl_void*)g, (lds_void*)(smem + xu * 1040));
        }
#pragma unroll
        for (int i = 0; i < 12; ++i) {
            const int v = wave * 12 + i;
            const _Float16* g = Wfrag + (size_t)(c * 48 + v) * 512 + lane * 8;
            async_ld16((gbl_void*)g, (lds_void*)&Ws[v * 512]);
        }
        __syncthreads();   // vmcnt(0) drain => DMA complete

#pragma unroll
        for (int s = 0; s < 4; ++s) {
            const int row = mt * 16 + lid;
            const int xoff = (row >> 1) * 1040 + (row & 1) * 512
                             + (s * 32 + quad * 8) * 4;
            const f32x4 alo = *(const f32x4*)(smem + xoff);
            const f32x4 ahi = *(const f32x4*)(smem + xoff + 16);
            f16x8 a;
#pragma unroll
            for (int j = 0; j < 4; ++j) {
                a[j]     = (_Float16)alo[j];
                a[4 + j] = (_Float16)ahi[j];
            }
#pragma unroll
            for (int j = 0; j < 6; ++j) {
                const int v = (nh * 6 + j) * 4 + s;
                const f16x8 b = *(const f16x8*)&Ws[v * 512 + lane * 8];
                acc[j] = __builtin_amdgcn_mfma_f32_16x16x32_f16(a, b, acc[j], 0, 0, 0);
            }
        }
    }
    __syncthreads();   // all staging reads done before overlay writes

#pragma unroll
    for (int j = 0; j < 6; ++j)
#pragma unroll
        for (int r = 0; r < 4; ++r)
            CsH[mt * 16 + quad * 4 + r][(nh * 6 + j) * 16 + lid] = (_Float16)acc[j][r];
    __syncthreads();

    {
        const int row = t >> 3;          // 0..31
        const int c8  = (t & 7) * 8;     // 0..56
        const size_t orow = (size_t)(m0 + row) * HS_;
        *(int4*)&qf[orow + c8] = *(int4*)&CsH[row][c8];
        *(int4*)&kf[orow + c8] = *(int4*)&CsH[row][64 + c8];
    }
    {
        const int h  = t >> 2;           // 0..63
        const int mo = (t & 3) * 8;      // 0..24
        _Float16 tmp[8];
#pragma unroll
        for (int j = 0; j < 8; ++j) tmp[j] = CsH[mo + j][128 + h];
        const int bi = m0 >> 11, m0loc = m0 & 2047;
        *(int4*)&vT[(size_t)(bi * 64 + h) * T_ + m0loc + mo] = *(int4*)&tmp[0];
    }
}

// ---------------------------------------------------------------------------
// Stage 2: causal flash attention — wave-autonomous, ZERO barriers.
// Split-K chunks of 4 k-tiles (grid 144 x 8, same decode as Round 7).
// Wave w owns q-rows 16w..16w+15.  K/V^T fragments load DIRECTLY from
// global (kf/vT are L2/L3-resident, frag pattern is 16-row x 64 B blocks).
// S^T = K.Q^T so softmax rows live per-lane (q = lid): row stats need only
// 2 shfls; alpha is a per-lane scalar.  P packs as 4 ds_write_b64 into a
// wave-private LDS slice; PV = MFMA(A=V^T, B=P rows) accumulates O^T;
// one wave-private LDS transpose at the epilogue restores coalesced output.
// LDS 18.4 KB, no __syncthreads anywhere.
// ---------------------------------------------------------------------------
__global__ __launch_bounds__(256) void attn_kernel(
    const _Float16* __restrict__ qf, const _Float16* __restrict__ kf,
    const _Float16* __restrict__ vT, _Float16* __restrict__ Opart,
    float* __restrict__ ml, float* __restrict__ out)
{
    // per-wave 4608 B union: Ps f16[16][72] (2304 B) / Osc f32[16][68] (4352 B)
    __shared__ __align__(16) char smem[4 * 4608];

    const int p = blockIdx.x, b = blockIdx.y;
    int g = 0;
    while (p >= 2 * (g + 1) * (g + 2)) ++g;
    const int rem = p - 2 * g * (g + 1);
    const int qi  = 4 * g + rem / (g + 1);
    const int cc  = rem % (g + 1);
    const int kts = cc * 4;
    const int kte = min(qi + 1, kts + 4);

    const int q0 = qi * 64;
    const size_t bT = (size_t)b * T_;
    const int t = threadIdx.x;
    const int lane = t & 63, wave = t >> 6;
    const int lid = lane & 15, quad = lane >> 4;

    _Float16* Ps  = (_Float16*)(smem + wave * 4608);   // [16][72] halves
    float*    Osc = (float*)(smem + wave * 4608);      // [16][68] floats

    // Q fragments straight from global (one-time)
    const size_t qrow = (bT + q0 + wave * 16 + lid) * HS_;
    const f16x8 aq0 = *(const f16x8*)&qf[qrow + quad * 8];
    const f16x8 aq1 = *(const f16x8*)&qf[qrow + 32 + quad * 8];

    f32x4 o[4];
#pragma unroll
    for (int i = 0; i < 4; ++i) o[i] = f32x4{0.f, 0.f, 0.f, 0.f};
    float mcur = -1e30f, lcur = 0.f;

    const float SC = 0.125f * 1.44269504088896f;   // HS^-0.5 * log2(e)

    for (int kt = kts; kt < kte; ++kt) {
        const int k0 = kt * 64;

        // K fragments (A-operand rows = k-rows), direct global
        f16x8 ka0[4], ka1[4];
#pragma unroll
        for (int nt = 0; nt < 4; ++nt) {
            const size_t kb = (bT + k0 + nt * 16 + lid) * HS_ + quad * 8;
            ka0[nt] = *(const f16x8*)&kf[kb];
            ka1[nt] = *(const f16x8*)&kf[kb + 32];
        }
        // V^T fragments (A-operand rows = h-rows), direct global; consumed
        // ~400 cyc later (after softmax) so latency self-hides
        f16x8 va0[4], va1[4];
#pragma unroll
        for (int ht = 0; ht < 4; ++ht) {
            const size_t vb = (size_t)(b * 64 + ht * 16 + lid) * T_ + k0 + quad * 8;
            va0[ht] = *(const f16x8*)&vT[vb];
            va1[ht] = *(const f16x8*)&vT[vb + 32];
        }

        // S^T = K.Q^T : tile nt covers k-rows nt*16..+15; C-layout q = lid
        f32x4 s[4];
#pragma unroll
        for (int i = 0; i < 4; ++i) s[i] = f32x4{0.f, 0.f, 0.f, 0.f};
#pragma unroll
        for (int nt = 0; nt < 4; ++nt) {
            s[nt] = __builtin_amdgcn_mfma_f32_16x16x32_f16(ka0[nt], aq0, s[nt], 0, 0, 0);
            s[nt] = __builtin_amdgcn_mfma_f32_16x16x32_f16(ka1[nt], aq1, s[nt], 0, 0, 0);
        }

        // scale + causal mask (diagonal tile only); k = k0+nt*16+quad*4+r, q fixed
        float sv[4][4];
        const bool diag = (kt == qi);
        const int qg = q0 + wave * 16 + lid;
#pragma unroll
        for (int nt = 0; nt < 4; ++nt)
#pragma unroll
            for (int r = 0; r < 4; ++r) {
                float v = s[nt][r] * SC;
                if (diag && (k0 + nt * 16 + quad * 4 + r > qg)) v = -1e30f;
                sv[nt][r] = v;
            }

        // per-lane row softmax: local 16-max + 2 shfls
        float pm = -1e30f;
#pragma unroll
        for (int nt = 0; nt < 4; ++nt)
#pragma unroll
            for (int r = 0; r < 4; ++r) pm = fmaxf(pm, sv[nt][r]);
        pm = fmaxf(pm, __shfl_xor(pm, 16, 64));
        pm = fmaxf(pm, __shfl_xor(pm, 32, 64));
        const float mn = fmaxf(mcur, pm);
        const float al = exp2f(mcur - mn);
        mcur = mn;
        float rs = 0.f;
#pragma unroll
        for (int nt = 0; nt < 4; ++nt)
#pragma unroll
            for (int r = 0; r < 4; ++r) {
                const float pv = exp2f(sv[nt][r] - mn);
                sv[nt][r] = pv;
                rs += pv;
            }
        rs += __shfl_xor(rs, 16, 64);
        rs += __shfl_xor(rs, 32, 64);
        lcur = lcur * al + rs;
#pragma unroll
        for (int nt = 0; nt < 4; ++nt)
#pragma unroll
            for (int r = 0; r < 4; ++r) o[nt][r] *= al;

        // P pack: P^T regs have r-contiguous k -> 4 x ds_write_b64
#pragma unroll
        for (int nt = 0; nt < 4; ++nt) {
            f16x4 p4;
#pragma unroll
            for (int r = 0; r < 4; ++r) p4[r] = (_Float16)sv[nt][r];
            *(f16x4*)&Ps[lid * 72 + nt * 16 + quad * 4] = p4;
        }

        // O^T += V^T . P^T : A = V^T frags, B = P rows (wave-private LDS)
        const f16x8 bp0 = *(const f16x8*)&Ps[lid * 72 + quad * 8];
        const f16x8 bp1 = *(const f16x8*)&Ps[lid * 72 + 32 + quad * 8];
#pragma unroll
        for (int ht = 0; ht < 4; ++ht) {
            o[ht] = __builtin_amdgcn_mfma_f32_16x16x32_f16(va0[ht], bp0, o[ht], 0, 0, 0);
            o[ht] = __builtin_amdgcn_mfma_f32_16x16x32_f16(va1[ht], bp1, o[ht], 0, 0, 0);
        }
    }

    // ---- epilogue: wave-private transpose O^T -> O, coalesced writes ----
    if (g == 0) {
        const float inv = 1.0f / lcur;
#pragma unroll
        for (int ht = 0; ht < 4; ++ht) {
            f32x4 ov;
#pragma unroll
            for (int r = 0; r < 4; ++r) ov[r] = o[ht][r] * inv;
            *(f32x4*)&Osc[lid * 68 + ht * 16 + quad * 4] = ov;
        }
        const int qr = lane >> 2, hc = (lane & 3) * 16;
#pragma unroll
        for (int i = 0; i < 4; ++i) {
            const f32x4 ov = *(const f32x4*)&Osc[qr * 68 + hc + i * 4];
            *(f32x4*)&out[(bT + q0 + wave * 16 + qr) * HS_ + hc + i * 4] = ov;
        }
    } else {
#pragma unroll
        for (int ht = 0; ht < 4; ++ht)
            *(f32x4*)&Osc[lid * 68 + ht * 16 + quad * 4] = o[ht];
        const int slot = b * 144 + p;
        _Float16* Ob = Opart + (size_t)slot * 4096;
        const int qr = lane >> 2, hc = (lane & 3) * 16;
        _Float16 tmp[16];
#pragma unroll
        for (int i = 0; i < 4; ++i) {
            const f32x4 ov = *(const f32x4*)&Osc[qr * 68 + hc + i * 4];
#pragma unroll
            for (int r = 0; r < 4; ++r) tmp[i * 4 + r] = (_Float16)ov[r];
        }
        *(int4*)&Ob[(wave * 16 + qr) * 64 + hc]     = *(int4*)&tmp[0];
        *(int4*)&Ob[(wave * 16 + qr) * 64 + hc + 8] = *(int4*)&tmp[8];
        if (lane < 16) {
            ml[(size_t)slot * 128 + wave * 16 + lane]      = mcur;
            ml[(size_t)slot * 128 + 64 + wave * 16 + lane] = lcur;
        }
    }
}

// ---------------------------------------------------------------------------
// Stage 3: combine partials for q-tiles with >=2 chunks (qi >= 4).
// (unchanged from Round 7)
// ---------------------------------------------------------------------------
__global__ __launch_bounds__(256) void combine_kernel(
    const _Float16* __restrict__ Opart, const float* __restrict__ ml,
    float* __restrict__ out)
{
    const int qi = 4 + blockIdx.x, b = blockIdx.y;
    const int g = qi >> 2, nc = g + 1;
    const int poff = 2 * g * (g + 1) + (qi & 3) * (g + 1);
    const int t = threadIdx.x, row = t >> 2, c0 = (t & 3) * 16;

    float mv[8], M = -1e30f;
#pragma unroll
    for (int cc = 0; cc < 8; ++cc) {
        mv[cc] = (cc < nc) ? ml[(size_t)(b * 144 + poff + cc) * 128 + row] : -1e30f;
        M = fmaxf(M, mv[cc]);
    }
    float L = 0.f, accv[16];
#pragma unroll
    for (int j = 0; j < 16; ++j) accv[j] = 0.f;
#pragma unroll
    for (int cc = 0; cc < 8; ++cc) {
        if (cc < nc) {   // nc is block-uniform: no divergence
            const int slot = b * 144 + poff + cc;
            const float w = exp2f(mv[cc] - M);
            L += ml[(size_t)slot * 128 + 64 + row] * w;
            f16x8 o0 = *(const f16x8*)&Opart[(size_t)slot * 4096 + row * 64 + c0];
            f16x8 o1 = *(const f16x8*)&Opart[(size_t)slot * 4096 + row * 64 + c0 + 8];
#pragma unroll
            for (int j = 0; j < 8; ++j) {
                accv[j]     += w * (float)o0[j];
                accv[8 + j] += w * (float)o1[j];
            }
        }
    }
    const float inv = 1.0f / L;
    const size_t obase = ((size_t)b * T_ + qi * 64 + row) * HS_ + c0;
#pragma unroll
    for (int u = 0; u < 4; ++u) {
        float4 r4;
        r4.x = accv[u * 4 + 0] * inv;
        r4.y = accv[u * 4 + 1] * inv;
        r4.z = accv[u * 4 + 2] * inv;
        r4.w = accv[u * 4 + 3] * inv;
        *(float4*)&out[obase + u * 4] = r4;
    }
}

// ---------------------------------------------------------------------------
extern "C" void kernel_launch(void* const* d_in, const int* in_sizes, int n_in,
                              void* d_out, int out_size, void* d_ws, size_t ws_size,
                              hipStream_t stream)
{
    const float* x  = (const float*)d_in[0];
    const float* Wq = (const float*)d_in[1];
    const float* Wk = (const float*)d_in[2];
    const float* Wv = (const float*)d_in[3];
    float* out = (float*)d_out;

    _Float16* w     = (_Float16*)d_ws;
    _Float16* qf    = w;
    _Float16* kf    = w + 1048576;
    _Float16* vT    = w + 2097152;
    _Float16* Wfrag = w + 3145728;
    _Float16* Op    = w + 3342336;            // + 196,608
    float*    ml    = (float*)(w + 8060928);  // Op + 4,718,592

    wt_kernel<<<dim3(16, 3), 256, 0, stream>>>(Wq, Wk, Wv, Wfrag);
    qkv_kernel<<<512, 256, 0, stream>>>(x, Wfrag, qf, kf, vT);
    attn_kernel<<<dim3(144, 8), 256, 0, stream>>>(qf, kf, vT, Op, ml, out);
    combine_kernel<<<dim3(28, 8), 256, 0, stream>>>(Op, ml, out);
}

// Round 9
// 132.540 us; speedup vs baseline: 1.1911x; 1.1911x over previous
//
#include <hip/hip_runtime.h>
#include <math.h>

#define B_ 8
#define T_ 2048
#define D_ 1024
#define HS_ 64

typedef _Float16 f16x8 __attribute__((ext_vector_type(8)));
typedef _Float16 f16x4 __attribute__((ext_vector_type(4)));
typedef float f32x4 __attribute__((ext_vector_type(4)));

typedef __attribute__((address_space(3))) void       lds_void;
typedef const __attribute__((address_space(1))) void gbl_void;
__device__ static inline void async_ld16(gbl_void* g, lds_void* l) {
    // 16 B per lane, HW dest = lds_base + lane*16 (wave-uniform base)
    __builtin_amdgcn_global_load_lds(g, l, 16, 0, 0);
}

// ---------------------------------------------------------------------------
// ws layout (f16 elements unless noted):
//   qf    : [B*T][64]        @ 0          (1,048,576)
//   kf    : [B*T][64]        @ 1,048,576
//   vT    : [B][64][T]       @ 2,097,152
//   Wfrag : fragment-packed  @ 3,145,728  (196,608)
//   Op    : [1152][64][64]   @ 3,342,336  (4,718,592) unnormalized O partials
//   ml    : [1152][128] f32  @ f16-idx 8,060,928  (m[64] then l[64] per slot)
// ---------------------------------------------------------------------------

// Stage 0: Wq|Wk|Wv (fp32 [1024][64]) -> Wfrag (f16, MFMA-fragment order)
__global__ __launch_bounds__(256) void wt_kernel(
    const float* __restrict__ Wq, const float* __restrict__ Wk,
    const float* __restrict__ Wv, _Float16* __restrict__ Wfrag)
{
    __shared__ _Float16 Tt[64][72];   // Tt[h][k_local]
    const int my = blockIdx.y;        // matrix 0,1,2
    const float* W = (my == 0) ? Wq : (my == 1) ? Wk : Wv;
    const int t  = threadIdx.x;
    const int kb = blockIdx.x;        // 64-k block
    const int k0 = kb * 64;
    {
        const int r = t >> 2, c0 = (t & 3) * 16;   // r = k row, c0 = h base
#pragma unroll
        for (int i = 0; i < 4; ++i) {
            float4 w = *(const float4*)&W[(size_t)(k0 + r) * HS_ + c0 + i * 4];
            Tt[c0 + i * 4 + 0][r] = (_Float16)w.x;
            Tt[c0 + i * 4 + 1][r] = (_Float16)w.y;
            Tt[c0 + i * 4 + 2][r] = (_Float16)w.z;
            Tt[c0 + i * 4 + 3][r] = (_Float16)w.w;
        }
    }
    __syncthreads();
    {
        const int lane = t & 63, j = t >> 6;       // j = n-tile within matrix
        const int lid = lane & 15, quad = lane >> 4;
        const int c = kb >> 1, shalf = kb & 1;
        const int nt = my * 4 + j;
#pragma unroll
        for (int s2 = 0; s2 < 2; ++s2) {
            const int u = (c * 12 + nt) * 4 + shalf * 2 + s2;
            *(int4*)&Wfrag[(size_t)u * 512 + lane * 8] =
                *(int4*)&Tt[j * 16 + lid][s2 * 32 + quad * 8];
        }
    }
}

// ---------------------------------------------------------------------------
// Stage 1: QKV projection (unchanged from Round 7).
// ---------------------------------------------------------------------------
__global__ __launch_bounds__(256, 2) void qkv_kernel(
    const float* __restrict__ x, const _Float16* __restrict__ Wfrag,
    _Float16* __restrict__ qf, _Float16* __restrict__ kf,
    _Float16* __restrict__ vT)
{
    __shared__ __align__(16) char smem[65792];        // Xs 16640 | Ws 49152
    _Float16* Ws = (_Float16*)(smem + 16640);
    _Float16 (*CsH)[200] = (_Float16(*)[200])smem;     // epilogue overlay

    const int t    = threadIdx.x;
    const int m0   = blockIdx.x * 32;
    const int lane = t & 63, wave = t >> 6;
    const int lid  = lane & 15, quad = lane >> 4;
    const int mt   = wave & 1;          // row group (16 rows)
    const int nh   = wave >> 1;         // n-half (6 n-tiles)

    f32x4 acc[6];
#pragma unroll
    for (int i = 0; i < 6; ++i) acc[i] = f32x4{0.f, 0.f, 0.f, 0.f};

    for (int c = 0; c < 8; ++c) {
        const int kc = c * 128;
        __syncthreads();   // previous chunk's LDS reads complete
#pragma unroll
        for (int i = 0; i < 4; ++i) {
            const int xu = wave * 4 + i;
            const float* g = x + (size_t)(m0 + xu * 2 + (lane >> 5)) * D_
                             + kc + (lane & 31) * 4;
            async_ld16((gbl_void*)g, (lds_void*)(smem + xu * 1040));
        }
#pragma unroll
        for (int i = 0; i < 12; ++i) {
            const int v = wave * 12 + i;
            const _Float16* g = Wfrag + (size_t)(c * 48 + v) * 512 + lane * 8;
            async_ld16((gbl_void*)g, (lds_void*)&Ws[v * 512]);
        }
        __syncthreads();   // vmcnt(0) drain => DMA complete

#pragma unroll
        for (int s = 0; s < 4; ++s) {
            const int row = mt * 16 + lid;
            const int xoff = (row >> 1) * 1040 + (row & 1) * 512
                             + (s * 32 + quad * 8) * 4;
            const f32x4 alo = *(const f32x4*)(smem + xoff);
            const f32x4 ahi = *(const f32x4*)(smem + xoff + 16);
            f16x8 a;
#pragma unroll
            for (int j = 0; j < 4; ++j) {
                a[j]     = (_Float16)alo[j];
                a[4 + j] = (_Float16)ahi[j];
            }
#pragma unroll
            for (int j = 0; j < 6; ++j) {
                const int v = (nh * 6 + j) * 4 + s;
                const f16x8 b = *(const f16x8*)&Ws[v * 512 + lane * 8];
                acc[j] = __builtin_amdgcn_mfma_f32_16x16x32_f16(a, b, acc[j], 0, 0, 0);
            }
        }
    }
    __syncthreads();   // all staging reads done before overlay writes

#pragma unroll
    for (int j = 0; j < 6; ++j)
#pragma unroll
        for (int r = 0; r < 4; ++r)
            CsH[mt * 16 + quad * 4 + r][(nh * 6 + j) * 16 + lid] = (_Float16)acc[j][r];
    __syncthreads();

    {
        const int row = t >> 3;          // 0..31
        const int c8  = (t & 7) * 8;     // 0..56
        const size_t orow = (size_t)(m0 + row) * HS_;
        *(int4*)&qf[orow + c8] = *(int4*)&CsH[row][c8];
        *(int4*)&kf[orow + c8] = *(int4*)&CsH[row][64 + c8];
    }
    {
        const int h  = t >> 2;           // 0..63
        const int mo = (t & 3) * 8;      // 0..24
        _Float16 tmp[8];
#pragma unroll
        for (int j = 0; j < 8; ++j) tmp[j] = CsH[mo + j][128 + h];
        const int bi = m0 >> 11, m0loc = m0 & 2047;
        *(int4*)&vT[(size_t)(bi * 64 + h) * T_ + m0loc + mo] = *(int4*)&tmp[0];
    }
}

// ---------------------------------------------------------------------------
// Stage 2: causal flash attention.  R7 staging skeleton (shared LDS tiles,
// int4 reg prefetch, 2 barriers/iter, split-K chunks of 4 k-tiles) + R8's
// transposed math: S^T = K.Q^T (same LDS reads, per-lane softmax rows ->
// 2 shfls), P packed as 4 ds_write_b64 wave-private, O^T = V^T.P^T,
// epilogue transpose through the dead P slice.
// ---------------------------------------------------------------------------
__global__ __launch_bounds__(256, 4) void attn_kernel(
    const _Float16* __restrict__ qf, const _Float16* __restrict__ kf,
    const _Float16* __restrict__ vT, _Float16* __restrict__ Opart,
    float* __restrict__ ml, float* __restrict__ out)
{
    __shared__ _Float16 Qs[64][72];
    __shared__ _Float16 Ks[64][72];
    __shared__ _Float16 Vts[64][72];
    __shared__ __align__(16) _Float16 Pw[4][16][72];   // wave-private P / scratch

    const int p = blockIdx.x, b = blockIdx.y;
    int g = 0;
    while (p >= 2 * (g + 1) * (g + 2)) ++g;
    const int rem = p - 2 * g * (g + 1);
    const int qi  = 4 * g + rem / (g + 1);
    const int cc  = rem % (g + 1);
    const int kts = cc * 4;
    const int kte = min(qi + 1, kts + 4);

    const int q0 = qi * 64;
    const size_t bT = (size_t)b * T_;
    const int t = threadIdx.x;
    const int lane = t & 63, wave = t >> 6;
    const int lid  = lane & 15, quad = lane >> 4;
    const int sr = t >> 2, so = (t & 3) * 16;

    // stage Q tile once
    {
        const size_t src = (bT + q0 + sr) * HS_ + so;
        *(int4*)&Qs[sr][so]     = *(const int4*)&qf[src];
        *(int4*)&Qs[sr][so + 8] = *(const int4*)&qf[src + 8];
    }
    __syncthreads();
    // Q as B-operand: lane holds q = lid, k = quad*8..+7 (+32)
    const f16x8 aq0 = *(const f16x8*)&Qs[wave * 16 + lid][quad * 8];
    const f16x8 aq1 = *(const f16x8*)&Qs[wave * 16 + lid][32 + quad * 8];

    f32x4 o[4];          // O^T: o[ht][r] = O[q=lid][h=ht*16+quad*4+r]
#pragma unroll
    for (int i = 0; i < 4; ++i) o[i] = f32x4{0.f, 0.f, 0.f, 0.f};
    float mcur = -1e30f, lcur = 0.f;

    const float SC = 0.125f * 1.44269504088896f;   // HS^-0.5 * log2(e)

    int4 kr0, kr1, vr0, vr1;
    {
        const int k0 = kts * 64;
        const size_t ksrc = (bT + k0 + sr) * HS_ + so;
        kr0 = *(const int4*)&kf[ksrc]; kr1 = *(const int4*)&kf[ksrc + 8];
        const size_t vsrc = (size_t)(b * 64 + sr) * T_ + k0 + so;
        vr0 = *(const int4*)&vT[vsrc]; vr1 = *(const int4*)&vT[vsrc + 8];
    }

    for (int kt = kts; kt < kte; ++kt) {
        __syncthreads();   // previous iteration done reading Ks/Vts
        *(int4*)&Ks[sr][so]      = kr0;
        *(int4*)&Ks[sr][so + 8]  = kr1;
        *(int4*)&Vts[sr][so]     = vr0;
        *(int4*)&Vts[sr][so + 8] = vr1;
        __syncthreads();
        if (kt + 1 < kte) {
            const int k0n = (kt + 1) * 64;
            const size_t ksrc = (bT + k0n + sr) * HS_ + so;
            kr0 = *(const int4*)&kf[ksrc]; kr1 = *(const int4*)&kf[ksrc + 8];
            const size_t vsrc = (size_t)(b * 64 + sr) * T_ + k0n + so;
            vr0 = *(const int4*)&vT[vsrc]; vr1 = *(const int4*)&vT[vsrc + 8];
        }

        // S^T = K.Q^T : A = K rows (same LDS reads as before), B = Q frag
        f32x4 s[4];
#pragma unroll
        for (int i = 0; i < 4; ++i) s[i] = f32x4{0.f, 0.f, 0.f, 0.f};
#pragma unroll
        for (int nt = 0; nt < 4; ++nt) {
            const f16x8 ka0 = *(const f16x8*)&Ks[nt * 16 + lid][quad * 8];
            const f16x8 ka1 = *(const f16x8*)&Ks[nt * 16 + lid][32 + quad * 8];
            s[nt] = __builtin_amdgcn_mfma_f32_16x16x32_f16(ka0, aq0, s[nt], 0, 0, 0);
            s[nt] = __builtin_amdgcn_mfma_f32_16x16x32_f16(ka1, aq1, s[nt], 0, 0, 0);
        }

        // scale + causal mask; lane owns q = q0+wave*16+lid, k = k0+nt*16+quad*4+r
        float sv[4][4];
        const bool diag = (kt == qi);
        const int k0 = kt * 64;
        const int qg = q0 + wave * 16 + lid;
#pragma unroll
        for (int nt = 0; nt < 4; ++nt)
#pragma unroll
            for (int r = 0; r < 4; ++r) {
                float v = s[nt][r] * SC;
                if (diag && (k0 + nt * 16 + quad * 4 + r > qg)) v = -1e30f;
                sv[nt][r] = v;
            }

        // per-lane row softmax: local 16-reduce + 2 shfls
        float pm = -1e30f;
#pragma unroll
        for (int nt = 0; nt < 4; ++nt)
#pragma unroll
            for (int r = 0; r < 4; ++r) pm = fmaxf(pm, sv[nt][r]);
        pm = fmaxf(pm, __shfl_xor(pm, 16, 64));
        pm = fmaxf(pm, __shfl_xor(pm, 32, 64));
        const float mn = fmaxf(mcur, pm);
        const float al = exp2f(mcur - mn);
        mcur = mn;
        float rs = 0.f;
#pragma unroll
        for (int nt = 0; nt < 4; ++nt)
#pragma unroll
            for (int r = 0; r < 4; ++r) {
                const float pv = exp2f(sv[nt][r] - mn);
                sv[nt][r] = pv;
                rs += pv;
            }
        rs += __shfl_xor(rs, 16, 64);
        rs += __shfl_xor(rs, 32, 64);
        lcur = lcur * al + rs;
#pragma unroll
        for (int nt = 0; nt < 4; ++nt)
#pragma unroll
            for (int r = 0; r < 4; ++r) o[nt][r] *= al;

        // P pack: row q = lid, k contiguous -> 4 x ds_write_b64 (wave-private)
#pragma unroll
        for (int nt = 0; nt < 4; ++nt) {
            f16x4 p4;
#pragma unroll
            for (int r = 0; r < 4; ++r) p4[r] = (_Float16)sv[nt][r];
            *(f16x4*)&Pw[wave][lid][nt * 16 + quad * 4] = p4;
        }

        // O^T += V^T.P^T : A = V^T rows (same Vts reads), B = P rows
        const f16x8 bp0 = *(const f16x8*)&Pw[wave][lid][quad * 8];
        const f16x8 bp1 = *(const f16x8*)&Pw[wave][lid][32 + quad * 8];
#pragma unroll
        for (int ht = 0; ht < 4; ++ht) {
            const f16x8 va0 = *(const f16x8*)&Vts[ht * 16 + lid][quad * 8];
            const f16x8 va1 = *(const f16x8*)&Vts[ht * 16 + lid][32 + quad * 8];
            o[ht] = __builtin_amdgcn_mfma_f32_16x16x32_f16(va0, bp0, o[ht], 0, 0, 0);
            o[ht] = __builtin_amdgcn_mfma_f32_16x16x32_f16(va1, bp1, o[ht], 0, 0, 0);
        }
    }

    // ---- epilogue: transpose O^T through the dead wave-private P slice ----
    if (g == 0) {
        const float inv = 1.0f / lcur;       // per-lane (q = lid)
        float* Osc = (float*)&Pw[wave][0][0];   // 576 floats = 16 x 36
        const int qr = lane >> 2, hc = (lane & 3) * 8;
#pragma unroll
        for (int half = 0; half < 2; ++half) {
#pragma unroll
            for (int hh = 0; hh < 2; ++hh) {
                const int ht = half * 2 + hh;
                f32x4 ov;
#pragma unroll
                for (int r = 0; r < 4; ++r) ov[r] = o[ht][r] * inv;
                *(f32x4*)&Osc[lid * 36 + hh * 16 + quad * 4] = ov;
            }
            const f32x4 r0 = *(const f32x4*)&Osc[qr * 36 + hc];
            const f32x4 r1 = *(const f32x4*)&Osc[qr * 36 + hc + 4];
            float* op = &out[(bT + q0 + wave * 16 + qr) * HS_ + half * 32 + hc];
            *(f32x4*)op       = r0;
            *(f32x4*)(op + 4) = r1;
        }
    } else {
        _Float16* Ph = &Pw[wave][0][0];      // f16 [16][72]
#pragma unroll
        for (int ht = 0; ht < 4; ++ht) {
            f16x4 t4;
#pragma unroll
            for (int r = 0; r < 4; ++r) t4[r] = (_Float16)o[ht][r];
            *(f16x4*)&Ph[lid * 72 + ht * 16 + quad * 4] = t4;
        }
        const int slot = b * 144 + p;
        _Float16* Ob = Opart + (size_t)slot * 4096;
        const int qr = lane >> 2, hc = (lane & 3) * 16;
        const int4 w0 = *(const int4*)&Ph[qr * 72 + hc];
        const int4 w1 = *(const int4*)&Ph[qr * 72 + hc + 8];
        *(int4*)&Ob[(wave * 16 + qr) * 64 + hc]     = w0;
        *(int4*)&Ob[(wave * 16 + qr) * 64 + hc + 8] = w1;
        if (lane < 16) {
            ml[(size_t)slot * 128 + wave * 16 + lane]      = mcur;
            ml[(size_t)slot * 128 + 64 + wave * 16 + lane] = lcur;
        }
    }
}

// ---------------------------------------------------------------------------
// Stage 3: combine partials for q-tiles with >=2 chunks (qi >= 4).
// (unchanged from Round 7)
// ---------------------------------------------------------------------------
__global__ __launch_bounds__(256) void combine_kernel(
    const _Float16* __restrict__ Opart, const float* __restrict__ ml,
    float* __restrict__ out)
{
    const int qi = 4 + blockIdx.x, b = blockIdx.y;
    const int g = qi >> 2, nc = g + 1;
    const int poff = 2 * g * (g + 1) + (qi & 3) * (g + 1);
    const int t = threadIdx.x, row = t >> 2, c0 = (t & 3) * 16;

    float mv[8], M = -1e30f;
#pragma unroll
    for (int cc = 0; cc < 8; ++cc) {
        mv[cc] = (cc < nc) ? ml[(size_t)(b * 144 + poff + cc) * 128 + row] : -1e30f;
        M = fmaxf(M, mv[cc]);
    }
    float L = 0.f, accv[16];
#pragma unroll
    for (int j = 0; j < 16; ++j) accv[j] = 0.f;
#pragma unroll
    for (int cc = 0; cc < 8; ++cc) {
        if (cc < nc) {   // nc is block-uniform: no divergence
            const int slot = b * 144 + poff + cc;
            const float w = exp2f(mv[cc] - M);
            L += ml[(size_t)slot * 128 + 64 + row] * w;
            f16x8 o0 = *(const f16x8*)&Opart[(size_t)slot * 4096 + row * 64 + c0];
            f16x8 o1 = *(const f16x8*)&Opart[(size_t)slot * 4096 + row * 64 + c0 + 8];
#pragma unroll
            for (int j = 0; j < 8; ++j) {
                accv[j]     += w * (float)o0[j];
                accv[8 + j] += w * (float)o1[j];
            }
        }
    }
    const float inv = 1.0f / L;
    const size_t obase = ((size_t)b * T_ + qi * 64 + row) * HS_ + c0;
#pragma unroll
    for (int u = 0; u < 4; ++u) {
        float4 r4;
        r4.x = accv[u * 4 + 0] * inv;
        r4.y = accv[u * 4 + 1] * inv;
        r4.z = accv[u * 4 + 2] * inv;
        r4.w = accv[u * 4 + 3] * inv;
        *(float4*)&out[obase + u * 4] = r4;
    }
}

// ---------------------------------------------------------------------------
extern "C" void kernel_launch(void* const* d_in, const int* in_sizes, int n_in,
                              void* d_out, int out_size, void* d_ws, size_t ws_size,
                              hipStream_t stream)
{
    const float* x  = (const float*)d_in[0];
    const float* Wq = (const float*)d_in[1];
    const float* Wk = (const float*)d_in[2];
    const float* Wv = (const float*)d_in[3];
    float* out = (float*)d_out;

    _Float16* w     = (_Float16*)d_ws;
    _Float16* qf    = w;
    _Float16* kf    = w + 1048576;
    _Float16* vT    = w + 2097152;
    _Float16* Wfrag = w + 3145728;
    _Float16* Op    = w + 3342336;            // + 196,608
    float*    ml    = (float*)(w + 8060928);  // Op + 4,718,592

    wt_kernel<<<dim3(16, 3), 256, 0, stream>>>(Wq, Wk, Wv, Wfrag);
    qkv_kernel<<<512, 256, 0, stream>>>(x, Wfrag, qf, kf, vT);
    attn_kernel<<<dim3(144, 8), 256, 0, stream>>>(qf, kf, vT, Op, ml, out);
    combine_kernel<<<dim3(28, 8), 256, 0, stream>>>(Op, ml, out);
}